// Round 5
// baseline (1373.430 us; speedup 1.0000x reference)
//
#include <hip/hip_runtime.h>

#define S_LEN  1024
#define H_DIM  4096
#define NHEAD  32
#define HEAD_D 128
#define RANK   16

typedef __bf16 bf16x8 __attribute__((ext_vector_type(8)));
typedef float  f32x4  __attribute__((ext_vector_type(4)));
typedef unsigned short ushort8v __attribute__((ext_vector_type(8)));

#define GLOAD_LDS16(g, l) __builtin_amdgcn_global_load_lds( \
    (const __attribute__((address_space(1))) unsigned int*)(g), \
    (__attribute__((address_space(3))) unsigned int*)(l), 16, 0, 0)

__device__ const float NF4_TAB[16] = {
    -1.0f, -0.6961928009986877f, -0.5250730514526367f, -0.39491748809814453f,
    -0.28444138169288635f, -0.18477343022823334f, -0.09105003625154495f, 0.0f,
    0.07958029955625534f, 0.16093020141124725f, 0.24611230194568634f,
    0.33791524171829224f, 0.4407098591327667f, 0.5626170039176941f,
    0.7229568362236023f, 1.0f};

__device__ __forceinline__ unsigned short f2bf(float f) {
    unsigned int u = __builtin_bit_cast(unsigned int, f);
    u = (u + 0x7FFFu + ((u >> 16) & 1u)) >> 16;   // RNE
    return (unsigned short)u;
}

// ---------------- dequant NF4 + LoRA fold -> bf16 ----------------
// W'[o][i] = nf4[c]*am + sum_r la[i][r]*lb[r][o]
__device__ __forceinline__ void dequant_fold_body(
    const int* __restrict__ codes, const float* __restrict__ absmax,
    const float* __restrict__ la, const float* __restrict__ lb,
    unsigned short* __restrict__ out, long i) {
    int4 c0 = *(const int4*)(codes + i);
    int4 c1 = *(const int4*)(codes + i + 4);
    float am = absmax[i >> 6];
    int orow = (int)(i >> 12);          // H_DIM = 4096
    int col  = (int)(i & 4095);
    float lbv[16];
#pragma unroll
    for (int r = 0; r < 16; ++r) lbv[r] = lb[r * H_DIM + orow];
    const float4* lap = (const float4*)(la + (long)col * RANK);
    float fold[8];
#pragma unroll
    for (int e = 0; e < 8; ++e) {
        float4 a0 = lap[e * 4 + 0], a1 = lap[e * 4 + 1];
        float4 a2 = lap[e * 4 + 2], a3 = lap[e * 4 + 3];
        float s = a0.x * lbv[0] + a0.y * lbv[1] + a0.z * lbv[2] + a0.w * lbv[3]
                + a1.x * lbv[4] + a1.y * lbv[5] + a1.z * lbv[6] + a1.w * lbv[7]
                + a2.x * lbv[8] + a2.y * lbv[9] + a2.z * lbv[10] + a2.w * lbv[11]
                + a3.x * lbv[12] + a3.y * lbv[13] + a3.z * lbv[14] + a3.w * lbv[15];
        fold[e] = s;
    }
    ushort8v r;
    r[0] = f2bf(NF4_TAB[c0.x] * am + fold[0]);
    r[1] = f2bf(NF4_TAB[c0.y] * am + fold[1]);
    r[2] = f2bf(NF4_TAB[c0.z] * am + fold[2]);
    r[3] = f2bf(NF4_TAB[c0.w] * am + fold[3]);
    r[4] = f2bf(NF4_TAB[c1.x] * am + fold[4]);
    r[5] = f2bf(NF4_TAB[c1.y] * am + fold[5]);
    r[6] = f2bf(NF4_TAB[c1.z] * am + fold[6]);
    r[7] = f2bf(NF4_TAB[c1.w] * am + fold[7]);
    *(ushort8v*)(out + i) = r;
}

__global__ __launch_bounds__(256) void dequant3_fold_kernel(
    const int* __restrict__ c0, const int* __restrict__ c1, const int* __restrict__ c2,
    const float* __restrict__ a0, const float* __restrict__ a1, const float* __restrict__ a2,
    const float* __restrict__ la0, const float* __restrict__ la1, const float* __restrict__ la2,
    const float* __restrict__ lb0, const float* __restrict__ lb1, const float* __restrict__ lb2,
    unsigned short* __restrict__ out, long n) {
    int t = blockIdx.y;
    const int* codes = (t == 0) ? c0 : (t == 1) ? c1 : c2;
    const float* absmax = (t == 0) ? a0 : (t == 1) ? a1 : a2;
    const float* la = (t == 0) ? la0 : (t == 1) ? la1 : la2;
    const float* lb = (t == 0) ? lb0 : (t == 1) ? lb1 : lb2;
    long i = ((long)blockIdx.x * 256 + threadIdx.x) * 8;
    if (i >= n) return;
    dequant_fold_body(codes, absmax, la, lb, out + (size_t)t * n, i);
}

__global__ __launch_bounds__(256) void dequant_fold_kernel(
    const int* __restrict__ codes, const float* __restrict__ absmax,
    const float* __restrict__ la, const float* __restrict__ lb,
    unsigned short* __restrict__ out, long n) {
    long i = ((long)blockIdx.x * 256 + threadIdx.x) * 8;
    if (i >= n) return;
    dequant_fold_body(codes, absmax, la, lb, out, i);
}

// ---------------- f32 -> bf16 ----------------
__global__ __launch_bounds__(256) void f32_to_bf16_kernel(
    const float* __restrict__ in, unsigned short* __restrict__ out, long n) {
    long i = ((long)blockIdx.x * 256 + threadIdx.x) * 8;
    if (i >= n) return;
    float4 a = *(const float4*)(in + i);
    float4 b = *(const float4*)(in + i + 4);
    ushort8v r;
    r[0] = f2bf(a.x); r[1] = f2bf(a.y); r[2] = f2bf(a.z); r[3] = f2bf(a.w);
    r[4] = f2bf(b.x); r[5] = f2bf(b.y); r[6] = f2bf(b.z); r[7] = f2bf(b.w);
    *(ushort8v*)(out + i) = r;
}

// ---------------- transpose v (bf16 [S][H]) -> vT (bf16 [H][S]) ----------------
__global__ void transpose_bf16_kernel(const unsigned short* __restrict__ v,
                                      unsigned short* __restrict__ vt) {
    __shared__ unsigned short tile[32][33];
    int c0 = blockIdx.x * 32, s0 = blockIdx.y * 32;
    int tx = threadIdx.x, ty = threadIdx.y;
    tile[ty][tx] = v[(long)(s0 + ty) * H_DIM + c0 + tx];
    __syncthreads();
    vt[(long)(c0 + ty) * S_LEN + s0 + tx] = tile[tx][ty];
}

// ---------------- bf16 NT GEMM: C[m][n] = alpha*sum_k A[m][k]*B[n][k] (+bias[n]) ------
// m97 recipe: 128x128 tile, BK=32, unpadded LDS, global_load_lds width=16.
// mode 0: plain batched (z). mode 1: causal triangular grid (x=tri idx, z=head).
// mode 2: batched + K limited to bm+128 (causal PV).
// obf: 1 -> bf16 output, 0 -> fp32. bias (fp32, per out column, +z*4096) optional.
__global__ __launch_bounds__(256) void gemm_nt(
    const unsigned short* __restrict__ A, const unsigned short* __restrict__ B,
    void* __restrict__ Cv, const float* __restrict__ bias,
    int K, int lda, int ldb, int ldc,
    long strideA, long strideB, long strideC, float alpha, int mode, int obf) {
    int bm, bn;
    int k0e = K;
    if (mode == 1) {
        int i = blockIdx.x;
        int tm = (int)((sqrtf(8.f * i + 1.f) - 1.f) * 0.5f);
        if ((tm + 1) * (tm + 2) / 2 <= i) tm++;
        if (tm * (tm + 1) / 2 > i) tm--;
        int tn = i - tm * (tm + 1) / 2;
        bm = tm * 128; bn = tn * 128;
    } else {
        bm = blockIdx.y * 128; bn = blockIdx.x * 128;
        if (mode == 2) { int kl = bm + 128; if (kl < k0e) k0e = kl; }
    }
    const unsigned short* Ab = A + (long)blockIdx.z * strideA;
    const unsigned short* Bb = B + (long)blockIdx.z * strideB;
    const long coff = (long)blockIdx.z * strideC;
    __shared__ unsigned short As[128][32];   // UNPADDED: global_load_lds lane-order
    __shared__ unsigned short Bs[128][32];
    const int tid = threadIdx.x;
    const int lane = tid & 63, wid = tid >> 6;
    const int wm = (wid >> 1) * 64, wn = (wid & 1) * 64;
    const int sr = wid * 16 + (lane >> 2);
    const int sc = (lane & 3) * 8;
    const unsigned short* gA0 = Ab + (long)(bm + sr) * lda + sc;
    const unsigned short* gA1 = gA0 + (long)64 * lda;
    const unsigned short* gB0 = Bb + (long)(bn + sr) * ldb + sc;
    const unsigned short* gB1 = gB0 + (long)64 * ldb;
    unsigned short* lA0 = &As[wid * 16][0];
    unsigned short* lA1 = &As[64 + wid * 16][0];
    unsigned short* lB0 = &Bs[wid * 16][0];
    unsigned short* lB1 = &Bs[64 + wid * 16][0];
    f32x4 acc[4][4] = {};
    const int kq = (lane >> 4) * 8;
    const int rr = lane & 15;
    for (int k0 = 0; k0 < k0e; k0 += 32) {
        GLOAD_LDS16(gA0 + k0, lA0);
        GLOAD_LDS16(gA1 + k0, lA1);
        GLOAD_LDS16(gB0 + k0, lB0);
        GLOAD_LDS16(gB1 + k0, lB1);
        __syncthreads();
        bf16x8 af[4], bfr[4];
        for (int i = 0; i < 4; ++i) {
            uint4 ta = *(const uint4*)&As[wm + i * 16 + rr][kq];
            uint4 tb = *(const uint4*)&Bs[wn + i * 16 + rr][kq];
            af[i]  = __builtin_bit_cast(bf16x8, ta);
            bfr[i] = __builtin_bit_cast(bf16x8, tb);
        }
        for (int i = 0; i < 4; ++i)
            for (int j = 0; j < 4; ++j)
                acc[i][j] = __builtin_amdgcn_mfma_f32_16x16x32_bf16(
                    af[i], bfr[j], acc[i][j], 0, 0, 0);
        __syncthreads();
    }
    const int cr = (lane >> 4) * 4;
    const int cc = lane & 15;
    float bv[4];
#pragma unroll
    for (int j = 0; j < 4; ++j)
        bv[j] = bias ? bias[(long)blockIdx.z * H_DIM + bn + wn + j * 16 + cc] : 0.f;
    if (obf) {
        unsigned short* Cb = (unsigned short*)Cv + coff;
        for (int i = 0; i < 4; ++i)
            for (int j = 0; j < 4; ++j) {
                unsigned short* cp = Cb + (long)(bm + wm + i * 16 + cr) * ldc
                                        + (bn + wn + j * 16 + cc);
                for (int r = 0; r < 4; ++r)
                    cp[(long)r * ldc] = f2bf(acc[i][j][r] * alpha + bv[j]);
            }
    } else {
        float* Cb = (float*)Cv + coff;
        for (int i = 0; i < 4; ++i)
            for (int j = 0; j < 4; ++j) {
                float* cp = Cb + (long)(bm + wm + i * 16 + cr) * ldc
                               + (bn + wn + j * 16 + cc);
                for (int r = 0; r < 4; ++r)
                    cp[(long)r * ldc] = acc[i][j][r] * alpha + bv[j];
            }
    }
}

// ---------------- causal softmax row, writes bf16 P in-place ----------------
__global__ __launch_bounds__(256) void softmax_causal(float* __restrict__ scores) {
    long rowbase = (long)blockIdx.x * S_LEN;
    int i = blockIdx.x & (S_LEN - 1);
    int tid = threadIdx.x, lane = tid & 63, wid = tid >> 6;
    float* row = scores + rowbase;
    int L = i + 1;
    float v[4];
    float mx = -1e30f;
    for (int t = 0; t < 4; ++t) {
        int j = tid + (t << 8);
        v[t] = (j < L) ? row[j] : -1e30f;
        mx = fmaxf(mx, v[t]);
    }
    for (int off = 32; off; off >>= 1) mx = fmaxf(mx, __shfl_xor(mx, off));
    __shared__ float red[4], red2[4];
    if (lane == 0) red[wid] = mx;
    __syncthreads();
    mx = fmaxf(fmaxf(red[0], red[1]), fmaxf(red[2], red[3]));
    float e[4], sum = 0.f;
    for (int t = 0; t < 4; ++t) {
        int j = tid + (t << 8);
        e[t] = (j < L) ? __expf(v[t] - mx) : 0.f;
        sum += e[t];
    }
    for (int off = 32; off; off >>= 1) sum += __shfl_xor(sum, off);
    if (lane == 0) red2[wid] = sum;
    __syncthreads();
    sum = red2[0] + red2[1] + red2[2] + red2[3];
    float inv = 1.f / sum;
    unsigned short* prow = (unsigned short*)scores + rowbase * 2;
    for (int t = 0; t < 4; ++t) {
        int j = tid + (t << 8);
        prow[j] = f2bf(e[t] * inv);
    }
}

// ---------------- x (fp32, exact 2-pass) k-th select ----------------
__global__ __launch_bounds__(256, 2) void hist_x_hi(
    const float* __restrict__ src, long n4, unsigned int* __restrict__ hist) {
    __shared__ unsigned int lh[16384];
    int t = threadIdx.x;
    for (int b = t; b < 16384; b += 256) lh[b] = 0u;
    __syncthreads();
    long i = (long)blockIdx.x * 256 + t;
    long stride = (long)gridDim.x * 256;
    for (; i < n4; i += stride) {
        float4 v = *(const float4*)(src + i * 4);
        unsigned int u0 = (__builtin_bit_cast(unsigned int, v.x) & 0x7FFFFFFFu) >> 16;
        unsigned int u1 = (__builtin_bit_cast(unsigned int, v.y) & 0x7FFFFFFFu) >> 16;
        unsigned int u2 = (__builtin_bit_cast(unsigned int, v.z) & 0x7FFFFFFFu) >> 16;
        unsigned int u3 = (__builtin_bit_cast(unsigned int, v.w) & 0x7FFFFFFFu) >> 16;
        atomicAdd(&lh[u0 < 16384u ? u0 : 16383u], 1u);
        atomicAdd(&lh[u1 < 16384u ? u1 : 16383u], 1u);
        atomicAdd(&lh[u2 < 16384u ? u2 : 16383u], 1u);
        atomicAdd(&lh[u3 < 16384u ? u3 : 16383u], 1u);
    }
    __syncthreads();
    for (int b = t; b < 16384; b += 256) {
        unsigned int c = lh[b];
        if (c) atomicAdd(&hist[b], c);
    }
}

__global__ __launch_bounds__(256) void hist_x_lo(
    const float* __restrict__ src, long n4,
    const unsigned int* __restrict__ sel, unsigned int* __restrict__ hist) {
    unsigned int target = sel[0];
    long i = (long)blockIdx.x * 256 + threadIdx.x;
    long stride = (long)gridDim.x * 256;
    for (; i < n4; i += stride) {
        float4 v = *(const float4*)(src + i * 4);
        unsigned int u0 = __builtin_bit_cast(unsigned int, v.x) & 0x7FFFFFFFu;
        unsigned int u1 = __builtin_bit_cast(unsigned int, v.y) & 0x7FFFFFFFu;
        unsigned int u2 = __builtin_bit_cast(unsigned int, v.z) & 0x7FFFFFFFu;
        unsigned int u3 = __builtin_bit_cast(unsigned int, v.w) & 0x7FFFFFFFu;
        if ((u0 >> 16) == target) atomicAdd(&hist[u0 & 0xFFFFu], 1u);
        if ((u1 >> 16) == target) atomicAdd(&hist[u1 & 0xFFFFu], 1u);
        if ((u2 >> 16) == target) atomicAdd(&hist[u2 & 0xFFFFu], 1u);
        if ((u3 >> 16) == target) atomicAdd(&hist[u3 & 0xFFFFu], 1u);
    }
}

// phase 0: hi bin + rank -> sel[0],sel[1]. phase 1: value bits -> *outp.
__global__ __launch_bounds__(256) void scan1(
    const unsigned int* __restrict__ hist, int bins, unsigned int* sel,
    float* outp, long k, int phase) {
    __shared__ unsigned int part[256];
    int t = threadIdx.x;
    int chunk = bins / 256;
    unsigned int s = 0;
    for (int b = 0; b < chunk; ++b) s += hist[t * chunk + b];
    part[t] = s;
    __syncthreads();
    if (t == 0) {
        long kk = (phase == 0) ? k : (long)sel[1];
        long c = 0;
        int ch = 0;
        for (; ch < 256; ++ch) {
            if (c + (long)part[ch] >= kk) break;
            c += part[ch];
        }
        int bin = ch * chunk;
        for (;; ++bin) {
            unsigned int h = hist[bin];
            if (c + (long)h >= kk) break;
            c += h;
        }
        if (phase == 0) { sel[0] = (unsigned int)bin; sel[1] = (unsigned int)(kk - c); }
        else *outp = __builtin_bit_cast(float, (sel[0] << 16) | (unsigned int)bin);
    }
}

// ---------------- bf16 tensors (q,k,v,o) exact 1-pass k-th of |.| ----------------
__global__ __launch_bounds__(256, 2) void hist4_bf16(
    const unsigned short* __restrict__ qkv, const unsigned short* __restrict__ ob,
    long n8, unsigned int* __restrict__ hist) {
    __shared__ unsigned int lh[16384];
    int t = threadIdx.x, ten = blockIdx.y;
    const unsigned short* src = (ten < 3) ? qkv + (size_t)ten * n8 * 8 : ob;
    unsigned int* gh = hist + (long)ten * 16384;
    for (int b = t; b < 16384; b += 256) lh[b] = 0u;
    __syncthreads();
    long i = (long)blockIdx.x * 256 + t;
    long stride = (long)gridDim.x * 256;
    for (; i < n8; i += stride) {
        ushort8v v = ((const ushort8v*)src)[i];
#pragma unroll
        for (int j = 0; j < 8; ++j) {
            unsigned int u = v[j] & 0x7FFFu;
            atomicAdd(&lh[u < 16384u ? u : 16383u], 1u);
        }
    }
    __syncthreads();
    for (int b = t; b < 16384; b += 256) {
        unsigned int c = lh[b];
        if (c) atomicAdd(&gh[b], c);
    }
}

__global__ __launch_bounds__(256) void scan4(
    const unsigned int* __restrict__ hist, float* __restrict__ out_kth, long k) {
    int ten = blockIdx.x;
    const unsigned int* h = hist + (long)ten * 16384;
    __shared__ unsigned int part[256];
    int t = threadIdx.x;
    unsigned int s = 0;
    for (int b = 0; b < 64; ++b) s += h[t * 64 + b];
    part[t] = s;
    __syncthreads();
    if (t == 0) {
        long c = 0;
        int ch = 0;
        for (; ch < 256; ++ch) {
            if (c + (long)part[ch] >= k) break;
            c += part[ch];
        }
        int bin = ch * 64;
        for (;; ++bin) {
            unsigned int hv = h[bin];
            if (c + (long)hv >= k) break;
            c += hv;
        }
        int slot = (ten == 3) ? 5 : ten + 1;     // q,k,v -> 1,2,3 ; o -> 5
        out_kth[slot] = __builtin_bit_cast(float, (unsigned int)bin << 16);
    }
}

// ---------------- P (softmax probs, bf16, row stride 2048) ----------------
__global__ __launch_bounds__(256, 2) void hist_bf16_p(
    const unsigned short* __restrict__ p, long nv, unsigned int* __restrict__ hist) {
    __shared__ unsigned int lh[16384];
    int t = threadIdx.x;
    for (int b = t; b < 16384; b += 256) lh[b] = 0u;
    __syncthreads();
    long i = (long)blockIdx.x * 256 + t;
    long stride = (long)gridDim.x * 256;
    unsigned int zc = 0;
    for (; i < nv; i += stride) {
        long r = i >> 7;
        int c = (int)(i & 127) * 8;
        ushort8v v = *(const ushort8v*)(p + (r << 11) + c);
#pragma unroll
        for (int j = 0; j < 8; ++j) {
            unsigned int b = v[j];
            if (b == 0) zc++;
            else atomicAdd(&lh[b < 16384u ? b : 16383u], 1u);
        }
    }
    if (zc) atomicAdd(&lh[0], zc);
    __syncthreads();
    for (int b = t; b < 16384; b += 256) {
        unsigned int c = lh[b];
        if (c) atomicAdd(&hist[b], c);
    }
}

__global__ __launch_bounds__(256) void scan_bf16(
    const unsigned int* __restrict__ hist, float* outp, long k) {
    __shared__ unsigned int part[256];
    int t = threadIdx.x;
    unsigned int s = 0;
    for (int b = 0; b < 64; ++b) s += hist[t * 64 + b];
    part[t] = s;
    __syncthreads();
    if (t == 0) {
        long c = 0;
        int ch = 0;
        for (; ch < 256; ++ch) {
            if (c + (long)part[ch] >= k) break;
            c += part[ch];
        }
        int bin = ch * 64;
        for (;; ++bin) {
            unsigned int h = hist[bin];
            if (c + (long)h >= k) break;
            c += h;
        }
        *outp = __builtin_bit_cast(float, (unsigned int)bin << 16);
    }
}

// ==================================================================
extern "C" void kernel_launch(void* const* d_in, const int* in_sizes, int n_in,
                              void* d_out, int out_size, void* d_ws, size_t ws_size,
                              hipStream_t stream) {
    (void)in_sizes; (void)n_in; (void)out_size; (void)ws_size;
    const float* x = (const float*)d_in[0];
    const int*   wcodes[4] = {(const int*)d_in[1], (const int*)d_in[6],
                              (const int*)d_in[11], (const int*)d_in[16]};
    const float* wabs[4]   = {(const float*)d_in[2], (const float*)d_in[7],
                              (const float*)d_in[12], (const float*)d_in[17]};
    const float* bias[4]   = {(const float*)d_in[3], (const float*)d_in[8],
                              (const float*)d_in[13], (const float*)d_in[18]};
    const float* lA[4]     = {(const float*)d_in[4], (const float*)d_in[9],
                              (const float*)d_in[14], (const float*)d_in[19]};
    const float* lB[4]     = {(const float*)d_in[5], (const float*)d_in[10],
                              (const float*)d_in[15], (const float*)d_in[20]};

    char* wp = (char*)d_ws;
    auto alloc = [&](size_t bytes) {
        char* p = wp; wp += (bytes + 255) & ~(size_t)255; return p;
    };
    const size_t SH  = (size_t)S_LEN * H_DIM;       // 4,194,304
    const long   nW  = (long)H_DIM * H_DIM;
    unsigned short* xb   = (unsigned short*)alloc(SH * 2);
    unsigned short* qkvb = (unsigned short*)alloc(3 * SH * 2);  // q,k,v bf16 contiguous
    unsigned short* vT   = (unsigned short*)alloc(SH * 2);
    unsigned short* ob   = (unsigned short*)alloc(SH * 2);
    unsigned short* Wd   = (unsigned short*)alloc((size_t)nW * 2);
    float*        bias3  = (float*)alloc(3 * H_DIM * 4);
    unsigned int* histH  = (unsigned int*)alloc(16384 * 4);     // x hi
    unsigned int* histL  = (unsigned int*)alloc(65536 * 4);     // x lo
    unsigned int* hist4  = (unsigned int*)alloc(4 * 16384 * 4); // q,k,v,o
    unsigned int* histP  = (unsigned int*)alloc(16384 * 4);
    unsigned int* sel    = (unsigned int*)alloc(256);
    // scores (128 MB) doubles as QKV dequant buffer (96 MB) before attention
    float* scores = (float*)alloc((size_t)NHEAD * S_LEN * S_LEN * 4);
    unsigned short* Wqkv = (unsigned short*)scores;

    float* out_final = (float*)d_out;
    float* out_kth   = out_final + SH;

    unsigned short* qb = qkvb;
    unsigned short* kb = qkvb + SH;
    unsigned short* vb = qkvb + 2 * SH;

    // x -> bf16 ; gather Q/K/V biases contiguous
    f32_to_bf16_kernel<<<2048, 256, 0, stream>>>(x, xb, (long)SH);
    for (int p = 0; p < 3; ++p)
        hipMemcpyAsync(bias3 + (size_t)p * H_DIM, bias[p], H_DIM * 4,
                       hipMemcpyDeviceToDevice, stream);

    // Q/K/V: dequant+LoRA-fold all 3 weights, then ONE z=3 batched GEMM -> bf16 + bias
    dequant3_fold_kernel<<<dim3(8192, 3), 256, 0, stream>>>(
        wcodes[0], wcodes[1], wcodes[2], wabs[0], wabs[1], wabs[2],
        lA[0], lA[1], lA[2], lB[0], lB[1], lB[2], Wqkv, nW);
    gemm_nt<<<dim3(32, 8, 3), 256, 0, stream>>>(
        xb, Wqkv, qkvb, bias3, H_DIM, H_DIM, H_DIM, H_DIM,
        0, nW, (long)SH, 1.0f, 0, 1);

    // v -> vT (both bf16)
    transpose_bf16_kernel<<<dim3(H_DIM / 32, S_LEN / 32), dim3(32, 32), 0, stream>>>(vb, vT);

    // scores = q.kT / sqrt(128): 36 lower-triangular tiles per head
    gemm_nt<<<dim3(36, 1, NHEAD), 256, 0, stream>>>(
        qb, kb, scores, nullptr, HEAD_D, H_DIM, H_DIM, S_LEN,
        128, 128, (long)S_LEN * S_LEN, 0.08838834764831845f, 1, 0);
    softmax_causal<<<NHEAD * S_LEN, 256, 0, stream>>>(scores);
    // o = P.v -> ob (bf16 direct); mode 2 limits K to bm+128
    gemm_nt<<<dim3(1, 8, NHEAD), 256, 0, stream>>>(
        (const unsigned short*)scores, vT, ob, nullptr, S_LEN,
        2 * S_LEN, S_LEN, H_DIM,
        (long)S_LEN * 2 * S_LEN, (long)HEAD_D * S_LEN, 128, 1.0f, 2, 1);

    // O projection -> d_out (fp32 + bias; LoRA folded into Wd)
    dequant_fold_kernel<<<8192, 256, 0, stream>>>(wcodes[3], wabs[3], lA[3], lB[3], Wd, nW);
    gemm_nt<<<dim3(32, 8, 1), 256, 0, stream>>>(
        ob, Wd, out_final, bias[3], H_DIM, H_DIM, H_DIM, H_DIM,
        0, 0, 0, 1.0f, 0, 0);

    // k-th smallest: x (fp32 exact 2-pass) -> slot 0
    hipMemsetAsync(histH, 0, 16384 * 4, stream);
    hist_x_hi<<<192, 256, 0, stream>>>(x, (long)SH / 4, histH);
    scan1<<<1, 256, 0, stream>>>(histH, 16384, sel, nullptr, (long)SH / 2, 0);
    hipMemsetAsync(histL, 0, 65536 * 4, stream);
    hist_x_lo<<<192, 256, 0, stream>>>(x, (long)SH / 4, sel, histL);
    scan1<<<1, 256, 0, stream>>>(histL, 65536, sel, out_kth + 0, 0, 1);
    // q,k,v,o (bf16 exact 1-pass) -> slots 1,2,3,5
    hipMemsetAsync(hist4, 0, 4 * 16384 * 4, stream);
    hist4_bf16<<<dim3(128, 4), 256, 0, stream>>>(qkvb, ob, (long)SH / 8, hist4);
    scan4<<<4, 256, 0, stream>>>(hist4, out_kth, (long)SH / 2);
    // P -> slot 4
    hipMemsetAsync(histP, 0, 16384 * 4, stream);
    hist_bf16_p<<<1024, 256, 0, stream>>>((const unsigned short*)scores,
                                          (long)NHEAD * S_LEN * S_LEN / 8, histP);
    scan_bf16<<<1, 256, 0, stream>>>(histP, out_kth + 4,
                                     (long)NHEAD * S_LEN * S_LEN / 2);
}

// Round 6
// 960.897 us; speedup vs baseline: 1.4293x; 1.4293x over previous
//
#include <hip/hip_runtime.h>

#define S_LEN  1024
#define H_DIM  4096
#define NHEAD  32
#define HEAD_D 128
#define RANK   16
#define KE3    4160   // QKV extended K: 4096 + 3*16 + 16 pad (130 * 32)
#define KEO    4128   // O-proj extended K: 4096 + 16 + 16 pad (129 * 32)

typedef __bf16 bf16x8 __attribute__((ext_vector_type(8)));
typedef float  f32x4  __attribute__((ext_vector_type(4)));
typedef unsigned short ushort8v __attribute__((ext_vector_type(8)));

#define GLOAD_LDS16(g, l) __builtin_amdgcn_global_load_lds( \
    (const __attribute__((address_space(1))) unsigned int*)(g), \
    (__attribute__((address_space(3))) unsigned int*)(l), 16, 0, 0)

__device__ const float NF4_TAB[16] = {
    -1.0f, -0.6961928009986877f, -0.5250730514526367f, -0.39491748809814453f,
    -0.28444138169288635f, -0.18477343022823334f, -0.09105003625154495f, 0.0f,
    0.07958029955625534f, 0.16093020141124725f, 0.24611230194568634f,
    0.33791524171829224f, 0.4407098591327667f, 0.5626170039176941f,
    0.7229568362236023f, 1.0f};

__device__ __forceinline__ unsigned short f2bf(float f) {
    unsigned int u = __builtin_bit_cast(unsigned int, f);
    u = (u + 0x7FFFu + ((u >> 16) & 1u)) >> 16;   // RNE
    return (unsigned short)u;
}

__device__ __forceinline__ float bf2f(unsigned short s) {
    return __builtin_bit_cast(float, (unsigned int)s << 16);
}

// ---------------- plain dequant NF4 -> bf16, strided output row ----------------
__device__ __forceinline__ void dequant_body(
    const int* __restrict__ codes, const float* __restrict__ absmax,
    unsigned short* __restrict__ out, long i, int ostride) {
    int4 c0 = *(const int4*)(codes + i);
    int4 c1 = *(const int4*)(codes + i + 4);
    float am = absmax[i >> 6];
    long orow = i >> 12;                 // H_DIM = 4096
    int  col  = (int)(i & 4095);
    ushort8v r;
    r[0] = f2bf(NF4_TAB[c0.x] * am);
    r[1] = f2bf(NF4_TAB[c0.y] * am);
    r[2] = f2bf(NF4_TAB[c0.z] * am);
    r[3] = f2bf(NF4_TAB[c0.w] * am);
    r[4] = f2bf(NF4_TAB[c1.x] * am);
    r[5] = f2bf(NF4_TAB[c1.y] * am);
    r[6] = f2bf(NF4_TAB[c1.z] * am);
    r[7] = f2bf(NF4_TAB[c1.w] * am);
    *(ushort8v*)(out + orow * ostride + col) = r;
}

__global__ __launch_bounds__(256) void dequant3_kernel(
    const int* __restrict__ c0, const int* __restrict__ c1, const int* __restrict__ c2,
    const float* __restrict__ a0, const float* __restrict__ a1, const float* __restrict__ a2,
    unsigned short* __restrict__ out, long n) {
    int t = blockIdx.y;
    const int* codes = (t == 0) ? c0 : (t == 1) ? c1 : c2;
    const float* absmax = (t == 0) ? a0 : (t == 1) ? a1 : a2;
    long i = ((long)blockIdx.x * 256 + threadIdx.x) * 8;
    if (i >= n) return;
    dequant_body(codes, absmax, out + (size_t)t * H_DIM * KE3, i, KE3);
}

__global__ __launch_bounds__(256) void dequant_o_kernel(
    const int* __restrict__ codes, const float* __restrict__ absmax,
    unsigned short* __restrict__ out, long n) {
    long i = ((long)blockIdx.x * 256 + threadIdx.x) * 8;
    if (i >= n) return;
    dequant_body(codes, absmax, out, i, KEO);
}

// ---------------- write lbT + zero pad cols into B_ext matrices ----------------
// p<3: Wqkv_ext tensor p, cols 4096..4159: lbT_p at 4096+16p, zeros elsewhere.
// p=3: Wd_ext, cols 4096..4127: lbT_o at 4096, zeros at 4112..4127.
__global__ __launch_bounds__(256) void lbt_writer(
    const float* __restrict__ lb0, const float* __restrict__ lb1,
    const float* __restrict__ lb2, const float* __restrict__ lb3,
    unsigned short* __restrict__ wqkv, unsigned short* __restrict__ wo) {
    int p = blockIdx.y;
    long g = (long)blockIdx.x * 256 + threadIdx.x;
    if (p < 3) {
        int row = (int)(g >> 6), c = (int)(g & 63);
        const float* lb = (p == 0) ? lb0 : (p == 1) ? lb1 : lb2;
        unsigned int r = (unsigned int)(c - 16 * p);
        float v = (r < 16u) ? lb[r * H_DIM + row] : 0.f;
        wqkv[(size_t)p * H_DIM * KE3 + (long)row * KE3 + 4096 + c] = f2bf(v);
    } else {
        if (g >= (long)H_DIM * 32) return;
        int row = (int)(g >> 5), c = (int)(g & 31);
        float v = (c < 16) ? lb3[c * H_DIM + row] : 0.f;
        wo[(long)row * KEO + 4096 + c] = f2bf(v);
    }
}

// ---------------- x (fp32) -> bf16 into stride-KE3 rows ----------------
__global__ __launch_bounds__(256) void cast_x_kernel(
    const float* __restrict__ in, unsigned short* __restrict__ out, long n) {
    long i = ((long)blockIdx.x * 256 + threadIdx.x) * 8;
    if (i >= n) return;
    float4 a = *(const float4*)(in + i);
    float4 b = *(const float4*)(in + i + 4);
    long row = i >> 12;
    int col = (int)(i & 4095);
    ushort8v r;
    r[0] = f2bf(a.x); r[1] = f2bf(a.y); r[2] = f2bf(a.z); r[3] = f2bf(a.w);
    r[4] = f2bf(b.x); r[5] = f2bf(b.y); r[6] = f2bf(b.z); r[7] = f2bf(b.w);
    *(ushort8v*)(out + row * KE3 + col) = r;
}

// ---------------- transpose v (bf16 [S][H]) -> vT (bf16 [H][S]) ----------------
__global__ void transpose_bf16_kernel(const unsigned short* __restrict__ v,
                                      unsigned short* __restrict__ vt) {
    __shared__ unsigned short tile[32][33];
    int c0 = blockIdx.x * 32, s0 = blockIdx.y * 32;
    int tx = threadIdx.x, ty = threadIdx.y;
    tile[ty][tx] = v[(long)(s0 + ty) * H_DIM + c0 + tx];
    __syncthreads();
    vt[(long)(c0 + ty) * S_LEN + s0 + tx] = tile[tx][ty];
}

// ---------------- xa = x @ la (fp32 in) -> bf16 cols of xb_ext ----------------
__global__ __launch_bounds__(256) void lora_a3_kernel(
    const float* __restrict__ x, const float* __restrict__ la0,
    const float* __restrict__ la1, const float* __restrict__ la2,
    unsigned short* __restrict__ xb_ext) {
    int p = blockIdx.y, m = blockIdx.x;
    const float* la = (p == 0) ? la0 : (p == 1) ? la1 : la2;
    const float* xr = x + (long)m * H_DIM;
    int tid = threadIdx.x, lane = tid & 63, wid = tid >> 6;
    float s[4] = {0.f, 0.f, 0.f, 0.f};
    for (int k = lane; k < H_DIM; k += 64) {
        float xv = xr[k];
        const float* lr = la + (long)k * RANK + wid * 4;
        s[0] += xv * lr[0]; s[1] += xv * lr[1];
        s[2] += xv * lr[2]; s[3] += xv * lr[3];
    }
    for (int off = 32; off; off >>= 1)
        for (int r = 0; r < 4; ++r) s[r] += __shfl_down(s[r], off);
    if (lane == 0)
        for (int r = 0; r < 4; ++r)
            xb_ext[(long)m * KE3 + 4096 + 16 * p + wid * 4 + r] = f2bf(s[r]);
}

// xa_o = ob @ la_o (bf16 in) -> bf16 cols of ob_ext
__global__ __launch_bounds__(256) void lora_ao_kernel(
    unsigned short* __restrict__ ob_ext, const float* __restrict__ la) {
    int m = blockIdx.x;
    const unsigned short* xr = ob_ext + (long)m * KEO;
    int tid = threadIdx.x, lane = tid & 63, wid = tid >> 6;
    float s[4] = {0.f, 0.f, 0.f, 0.f};
    for (int k = lane; k < H_DIM; k += 64) {
        float xv = bf2f(xr[k]);
        const float* lr = la + (long)k * RANK + wid * 4;
        s[0] += xv * lr[0]; s[1] += xv * lr[1];
        s[2] += xv * lr[2]; s[3] += xv * lr[3];
    }
    for (int off = 32; off; off >>= 1)
        for (int r = 0; r < 4; ++r) s[r] += __shfl_down(s[r], off);
    if (lane == 0)
        for (int r = 0; r < 4; ++r)
            ob_ext[(long)m * KEO + 4096 + wid * 4 + r] = f2bf(s[r]);
}

// ---------------- bf16 NT GEMM: C[m][n] = alpha*sum_k A[m][k]*B[n][k] (+bias[n]) ------
// m97 recipe: 128x128 tile, BK=32, unpadded LDS, global_load_lds width=16.
// mode 0: plain batched (z). mode 1: causal triangular grid (x=tri idx, z=head).
// mode 2: batched + K limited to bm+128 (causal PV).
// obf: 1 -> bf16 output, 0 -> fp32. bias (fp32, per out column, +z*4096) optional.
__global__ __launch_bounds__(256) void gemm_nt(
    const unsigned short* __restrict__ A, const unsigned short* __restrict__ B,
    void* __restrict__ Cv, const float* __restrict__ bias,
    int K, int lda, int ldb, int ldc,
    long strideA, long strideB, long strideC, float alpha, int mode, int obf) {
    int bm, bn;
    int k0e = K;
    if (mode == 1) {
        int i = blockIdx.x;
        int tm = (int)((sqrtf(8.f * i + 1.f) - 1.f) * 0.5f);
        if ((tm + 1) * (tm + 2) / 2 <= i) tm++;
        if (tm * (tm + 1) / 2 > i) tm--;
        int tn = i - tm * (tm + 1) / 2;
        bm = tm * 128; bn = tn * 128;
    } else {
        bm = blockIdx.y * 128; bn = blockIdx.x * 128;
        if (mode == 2) { int kl = bm + 128; if (kl < k0e) k0e = kl; }
    }
    const unsigned short* Ab = A + (long)blockIdx.z * strideA;
    const unsigned short* Bb = B + (long)blockIdx.z * strideB;
    const long coff = (long)blockIdx.z * strideC;
    __shared__ unsigned short As[128][32];   // UNPADDED: global_load_lds lane-order
    __shared__ unsigned short Bs[128][32];
    const int tid = threadIdx.x;
    const int lane = tid & 63, wid = tid >> 6;
    const int wm = (wid >> 1) * 64, wn = (wid & 1) * 64;
    const int sr = wid * 16 + (lane >> 2);
    const int sc = (lane & 3) * 8;
    const unsigned short* gA0 = Ab + (long)(bm + sr) * lda + sc;
    const unsigned short* gA1 = gA0 + (long)64 * lda;
    const unsigned short* gB0 = Bb + (long)(bn + sr) * ldb + sc;
    const unsigned short* gB1 = gB0 + (long)64 * ldb;
    unsigned short* lA0 = &As[wid * 16][0];
    unsigned short* lA1 = &As[64 + wid * 16][0];
    unsigned short* lB0 = &Bs[wid * 16][0];
    unsigned short* lB1 = &Bs[64 + wid * 16][0];
    f32x4 acc[4][4] = {};
    const int kq = (lane >> 4) * 8;
    const int rr = lane & 15;
    for (int k0 = 0; k0 < k0e; k0 += 32) {
        GLOAD_LDS16(gA0 + k0, lA0);
        GLOAD_LDS16(gA1 + k0, lA1);
        GLOAD_LDS16(gB0 + k0, lB0);
        GLOAD_LDS16(gB1 + k0, lB1);
        __syncthreads();
        bf16x8 af[4], bfr[4];
        for (int i = 0; i < 4; ++i) {
            uint4 ta = *(const uint4*)&As[wm + i * 16 + rr][kq];
            uint4 tb = *(const uint4*)&Bs[wn + i * 16 + rr][kq];
            af[i]  = __builtin_bit_cast(bf16x8, ta);
            bfr[i] = __builtin_bit_cast(bf16x8, tb);
        }
        for (int i = 0; i < 4; ++i)
            for (int j = 0; j < 4; ++j)
                acc[i][j] = __builtin_amdgcn_mfma_f32_16x16x32_bf16(
                    af[i], bfr[j], acc[i][j], 0, 0, 0);
        __syncthreads();
    }
    const int cr = (lane >> 4) * 4;
    const int cc = lane & 15;
    float bv[4];
#pragma unroll
    for (int j = 0; j < 4; ++j)
        bv[j] = bias ? bias[(long)blockIdx.z * H_DIM + bn + wn + j * 16 + cc] : 0.f;
    if (obf) {
        unsigned short* Cb = (unsigned short*)Cv + coff;
        for (int i = 0; i < 4; ++i)
            for (int j = 0; j < 4; ++j) {
                unsigned short* cp = Cb + (long)(bm + wm + i * 16 + cr) * ldc
                                        + (bn + wn + j * 16 + cc);
                for (int r = 0; r < 4; ++r)
                    cp[(long)r * ldc] = f2bf(acc[i][j][r] * alpha + bv[j]);
            }
    } else {
        float* Cb = (float*)Cv + coff;
        for (int i = 0; i < 4; ++i)
            for (int j = 0; j < 4; ++j) {
                float* cp = Cb + (long)(bm + wm + i * 16 + cr) * ldc
                               + (bn + wn + j * 16 + cc);
                for (int r = 0; r < 4; ++r)
                    cp[(long)r * ldc] = acc[i][j][r] * alpha + bv[j];
            }
    }
}

// ---------------- causal softmax row, writes bf16 P in-place ----------------
__global__ __launch_bounds__(256) void softmax_causal(float* __restrict__ scores) {
    long rowbase = (long)blockIdx.x * S_LEN;
    int i = blockIdx.x & (S_LEN - 1);
    int tid = threadIdx.x, lane = tid & 63, wid = tid >> 6;
    float* row = scores + rowbase;
    int L = i + 1;
    float v[4];
    float mx = -1e30f;
    for (int t = 0; t < 4; ++t) {
        int j = tid + (t << 8);
        v[t] = (j < L) ? row[j] : -1e30f;
        mx = fmaxf(mx, v[t]);
    }
    for (int off = 32; off; off >>= 1) mx = fmaxf(mx, __shfl_xor(mx, off));
    __shared__ float red[4], red2[4];
    if (lane == 0) red[wid] = mx;
    __syncthreads();
    mx = fmaxf(fmaxf(red[0], red[1]), fmaxf(red[2], red[3]));
    float e[4], sum = 0.f;
    for (int t = 0; t < 4; ++t) {
        int j = tid + (t << 8);
        e[t] = (j < L) ? __expf(v[t] - mx) : 0.f;
        sum += e[t];
    }
    for (int off = 32; off; off >>= 1) sum += __shfl_xor(sum, off);
    if (lane == 0) red2[wid] = sum;
    __syncthreads();
    sum = red2[0] + red2[1] + red2[2] + red2[3];
    float inv = 1.f / sum;
    unsigned short* prow = (unsigned short*)scores + rowbase * 2;
    for (int t = 0; t < 4; ++t) {
        int j = tid + (t << 8);
        prow[j] = f2bf(e[t] * inv);
    }
}

// ---------------- x (fp32, exact 2-pass) k-th select ----------------
__global__ __launch_bounds__(256, 2) void hist_x_hi(
    const float* __restrict__ src, long n4, unsigned int* __restrict__ hist) {
    __shared__ unsigned int lh[16384];
    int t = threadIdx.x;
    for (int b = t; b < 16384; b += 256) lh[b] = 0u;
    __syncthreads();
    long i = (long)blockIdx.x * 256 + t;
    long stride = (long)gridDim.x * 256;
    for (; i < n4; i += stride) {
        float4 v = *(const float4*)(src + i * 4);
        unsigned int u0 = (__builtin_bit_cast(unsigned int, v.x) & 0x7FFFFFFFu) >> 16;
        unsigned int u1 = (__builtin_bit_cast(unsigned int, v.y) & 0x7FFFFFFFu) >> 16;
        unsigned int u2 = (__builtin_bit_cast(unsigned int, v.z) & 0x7FFFFFFFu) >> 16;
        unsigned int u3 = (__builtin_bit_cast(unsigned int, v.w) & 0x7FFFFFFFu) >> 16;
        atomicAdd(&lh[u0 < 16384u ? u0 : 16383u], 1u);
        atomicAdd(&lh[u1 < 16384u ? u1 : 16383u], 1u);
        atomicAdd(&lh[u2 < 16384u ? u2 : 16383u], 1u);
        atomicAdd(&lh[u3 < 16384u ? u3 : 16383u], 1u);
    }
    __syncthreads();
    for (int b = t; b < 16384; b += 256) {
        unsigned int c = lh[b];
        if (c) atomicAdd(&hist[b], c);
    }
}

__global__ __launch_bounds__(256) void hist_x_lo(
    const float* __restrict__ src, long n4,
    const unsigned int* __restrict__ sel, unsigned int* __restrict__ hist) {
    unsigned int target = sel[0];
    long i = (long)blockIdx.x * 256 + threadIdx.x;
    long stride = (long)gridDim.x * 256;
    for (; i < n4; i += stride) {
        float4 v = *(const float4*)(src + i * 4);
        unsigned int u0 = __builtin_bit_cast(unsigned int, v.x) & 0x7FFFFFFFu;
        unsigned int u1 = __builtin_bit_cast(unsigned int, v.y) & 0x7FFFFFFFu;
        unsigned int u2 = __builtin_bit_cast(unsigned int, v.z) & 0x7FFFFFFFu;
        unsigned int u3 = __builtin_bit_cast(unsigned int, v.w) & 0x7FFFFFFFu;
        if ((u0 >> 16) == target) atomicAdd(&hist[u0 & 0xFFFFu], 1u);
        if ((u1 >> 16) == target) atomicAdd(&hist[u1 & 0xFFFFu], 1u);
        if ((u2 >> 16) == target) atomicAdd(&hist[u2 & 0xFFFFu], 1u);
        if ((u3 >> 16) == target) atomicAdd(&hist[u3 & 0xFFFFu], 1u);
    }
}

// phase 0: hi bin + rank -> sel[0],sel[1]. phase 1: value bits -> *outp.
__global__ __launch_bounds__(256) void scan1(
    const unsigned int* __restrict__ hist, int bins, unsigned int* sel,
    float* outp, long k, int phase) {
    __shared__ unsigned int part[256];
    int t = threadIdx.x;
    int chunk = bins / 256;
    unsigned int s = 0;
    for (int b = 0; b < chunk; ++b) s += hist[t * chunk + b];
    part[t] = s;
    __syncthreads();
    if (t == 0) {
        long kk = (phase == 0) ? k : (long)sel[1];
        long c = 0;
        int ch = 0;
        for (; ch < 256; ++ch) {
            if (c + (long)part[ch] >= kk) break;
            c += part[ch];
        }
        int bin = ch * chunk;
        for (;; ++bin) {
            unsigned int h = hist[bin];
            if (c + (long)h >= kk) break;
            c += h;
        }
        if (phase == 0) { sel[0] = (unsigned int)bin; sel[1] = (unsigned int)(kk - c); }
        else *outp = __builtin_bit_cast(float, (sel[0] << 16) | (unsigned int)bin);
    }
}

// ---------------- bf16 tensors (q,k,v,o) exact 1-pass k-th of |.| ----------------
// q,k,v contiguous [SH]; o strided: rows of 4096 valid in stride-KEO.
__global__ __launch_bounds__(256, 2) void hist4_bf16(
    const unsigned short* __restrict__ qkv, const unsigned short* __restrict__ ob,
    long n8, unsigned int* __restrict__ hist) {
    __shared__ unsigned int lh[16384];
    int t = threadIdx.x, ten = blockIdx.y;
    const unsigned short* src = (ten < 3) ? qkv + (size_t)ten * n8 * 8 : ob;
    unsigned int* gh = hist + (long)ten * 16384;
    for (int b = t; b < 16384; b += 256) lh[b] = 0u;
    __syncthreads();
    long i = (long)blockIdx.x * 256 + t;
    long stride = (long)gridDim.x * 256;
    for (; i < n8; i += stride) {
        long off = (ten == 3) ? ((i >> 9) * KEO + ((i & 511) << 3)) : (i << 3);
        ushort8v v = *(const ushort8v*)(src + off);
#pragma unroll
        for (int j = 0; j < 8; ++j) {
            unsigned int u = v[j] & 0x7FFFu;
            atomicAdd(&lh[u < 16384u ? u : 16383u], 1u);
        }
    }
    __syncthreads();
    for (int b = t; b < 16384; b += 256) {
        unsigned int c = lh[b];
        if (c) atomicAdd(&gh[b], c);
    }
}

__global__ __launch_bounds__(256) void scan4(
    const unsigned int* __restrict__ hist, float* __restrict__ out_kth, long k) {
    int ten = blockIdx.x;
    const unsigned int* h = hist + (long)ten * 16384;
    __shared__ unsigned int part[256];
    int t = threadIdx.x;
    unsigned int s = 0;
    for (int b = 0; b < 64; ++b) s += h[t * 64 + b];
    part[t] = s;
    __syncthreads();
    if (t == 0) {
        long c = 0;
        int ch = 0;
        for (; ch < 256; ++ch) {
            if (c + (long)part[ch] >= k) break;
            c += part[ch];
        }
        int bin = ch * 64;
        for (;; ++bin) {
            unsigned int hv = h[bin];
            if (c + (long)hv >= k) break;
            c += hv;
        }
        int slot = (ten == 3) ? 5 : ten + 1;     // q,k,v -> 1,2,3 ; o -> 5
        out_kth[slot] = __builtin_bit_cast(float, (unsigned int)bin << 16);
    }
}

// ---------------- P (softmax probs, bf16, row stride 2048) ----------------
__global__ __launch_bounds__(256, 2) void hist_bf16_p(
    const unsigned short* __restrict__ p, long nv, unsigned int* __restrict__ hist) {
    __shared__ unsigned int lh[16384];
    int t = threadIdx.x;
    for (int b = t; b < 16384; b += 256) lh[b] = 0u;
    __syncthreads();
    long i = (long)blockIdx.x * 256 + t;
    long stride = (long)gridDim.x * 256;
    unsigned int zc = 0;
    for (; i < nv; i += stride) {
        long r = i >> 7;
        int c = (int)(i & 127) * 8;
        ushort8v v = *(const ushort8v*)(p + (r << 11) + c);
#pragma unroll
        for (int j = 0; j < 8; ++j) {
            unsigned int b = v[j];
            if (b == 0) zc++;
            else atomicAdd(&lh[b < 16384u ? b : 16383u], 1u);
        }
    }
    if (zc) atomicAdd(&lh[0], zc);
    __syncthreads();
    for (int b = t; b < 16384; b += 256) {
        unsigned int c = lh[b];
        if (c) atomicAdd(&hist[b], c);
    }
}

__global__ __launch_bounds__(256) void scan_bf16(
    const unsigned int* __restrict__ hist, float* outp, long k) {
    __shared__ unsigned int part[256];
    int t = threadIdx.x;
    unsigned int s = 0;
    for (int b = 0; b < 64; ++b) s += hist[t * 64 + b];
    part[t] = s;
    __syncthreads();
    if (t == 0) {
        long c = 0;
        int ch = 0;
        for (; ch < 256; ++ch) {
            if (c + (long)part[ch] >= k) break;
            c += part[ch];
        }
        int bin = ch * 64;
        for (;; ++bin) {
            unsigned int h = hist[bin];
            if (c + (long)h >= k) break;
            c += h;
        }
        *outp = __builtin_bit_cast(float, (unsigned int)bin << 16);
    }
}

// ==================================================================
extern "C" void kernel_launch(void* const* d_in, const int* in_sizes, int n_in,
                              void* d_out, int out_size, void* d_ws, size_t ws_size,
                              hipStream_t stream) {
    (void)in_sizes; (void)n_in; (void)out_size; (void)ws_size;
    const float* x = (const float*)d_in[0];
    const int*   wcodes[4] = {(const int*)d_in[1], (const int*)d_in[6],
                              (const int*)d_in[11], (const int*)d_in[16]};
    const float* wabs[4]   = {(const float*)d_in[2], (const float*)d_in[7],
                              (const float*)d_in[12], (const float*)d_in[17]};
    const float* bias[4]   = {(const float*)d_in[3], (const float*)d_in[8],
                              (const float*)d_in[13], (const float*)d_in[18]};
    const float* lA[4]     = {(const float*)d_in[4], (const float*)d_in[9],
                              (const float*)d_in[14], (const float*)d_in[19]};
    const float* lB[4]     = {(const float*)d_in[5], (const float*)d_in[10],
                              (const float*)d_in[15], (const float*)d_in[20]};

    char* wp = (char*)d_ws;
    auto alloc = [&](size_t bytes) {
        char* p = wp; wp += (bytes + 255) & ~(size_t)255; return p;
    };
    const size_t SH  = (size_t)S_LEN * H_DIM;       // 4,194,304
    const long   nW  = (long)H_DIM * H_DIM;
    unsigned short* xb_ext = (unsigned short*)alloc((size_t)S_LEN * KE3 * 2);
    unsigned short* qkvb   = (unsigned short*)alloc(3 * SH * 2);  // q,k,v bf16
    unsigned short* vT     = (unsigned short*)alloc(SH * 2);
    unsigned short* ob_ext = (unsigned short*)alloc((size_t)S_LEN * KEO * 2);
    unsigned short* Wd_ext = (unsigned short*)alloc((size_t)H_DIM * KEO * 2);
    float*        bias3  = (float*)alloc(3 * H_DIM * 4);
    unsigned int* histH  = (unsigned int*)alloc(16384 * 4);     // x hi
    unsigned int* histL  = (unsigned int*)alloc(65536 * 4);     // x lo
    unsigned int* hist4  = (unsigned int*)alloc(4 * 16384 * 4); // q,k,v,o
    unsigned int* histP  = (unsigned int*)alloc(16384 * 4);
    unsigned int* sel    = (unsigned int*)alloc(256);
    // scores (128 MB) doubles as Wqkv_ext buffer (102 MB) before attention
    float* scores = (float*)alloc((size_t)NHEAD * S_LEN * S_LEN * 4);
    unsigned short* Wqkv_ext = (unsigned short*)scores;

    float* out_final = (float*)d_out;
    float* out_kth   = out_final + SH;

    unsigned short* qb = qkvb;
    unsigned short* kb = qkvb + SH;
    unsigned short* vb = qkvb + 2 * SH;

    // A_ext: x cast + per-projection xa columns
    cast_x_kernel<<<2048, 256, 0, stream>>>(x, xb_ext, (long)SH);
    lora_a3_kernel<<<dim3(S_LEN, 3), 256, 0, stream>>>(x, lA[0], lA[1], lA[2], xb_ext);
    for (int p = 0; p < 3; ++p)
        hipMemcpyAsync(bias3 + (size_t)p * H_DIM, bias[p], H_DIM * 4,
                       hipMemcpyDeviceToDevice, stream);

    // B_ext: plain dequant (strided rows) + lbT/zero pad columns
    dequant3_kernel<<<dim3(8192, 3), 256, 0, stream>>>(
        wcodes[0], wcodes[1], wcodes[2], wabs[0], wabs[1], wabs[2], Wqkv_ext, nW);
    dequant_o_kernel<<<8192, 256, 0, stream>>>(wcodes[3], wabs[3], Wd_ext, nW);
    lbt_writer<<<dim3(1024, 4), 256, 0, stream>>>(
        lB[0], lB[1], lB[2], lB[3], Wqkv_ext, Wd_ext);

    // QKV: ONE z=3 batched GEMM over K=4160 (main + LoRA fused) -> bf16 + bias
    gemm_nt<<<dim3(32, 8, 3), 256, 0, stream>>>(
        xb_ext, Wqkv_ext, qkvb, bias3, KE3, KE3, KE3, H_DIM,
        0, (long)H_DIM * KE3, (long)SH, 1.0f, 0, 1);

    // v -> vT (both bf16)
    transpose_bf16_kernel<<<dim3(H_DIM / 32, S_LEN / 32), dim3(32, 32), 0, stream>>>(vb, vT);

    // scores = q.kT / sqrt(128): 36 lower-triangular tiles per head
    gemm_nt<<<dim3(36, 1, NHEAD), 256, 0, stream>>>(
        qb, kb, scores, nullptr, HEAD_D, H_DIM, H_DIM, S_LEN,
        128, 128, (long)S_LEN * S_LEN, 0.08838834764831845f, 1, 0);
    softmax_causal<<<NHEAD * S_LEN, 256, 0, stream>>>(scores);
    // o = P.v -> ob_ext (bf16, row stride KEO); mode 2 limits K to bm+128
    gemm_nt<<<dim3(1, 8, NHEAD), 256, 0, stream>>>(
        (const unsigned short*)scores, vT, ob_ext, nullptr, S_LEN,
        2 * S_LEN, S_LEN, KEO,
        (long)S_LEN * 2 * S_LEN, (long)HEAD_D * S_LEN, 128, 1.0f, 2, 1);

    // xa_o columns, then O projection over K=4128 -> d_out (fp32 + bias)
    lora_ao_kernel<<<S_LEN, 256, 0, stream>>>(ob_ext, lA[3]);
    gemm_nt<<<dim3(32, 8, 1), 256, 0, stream>>>(
        ob_ext, Wd_ext, out_final, bias[3], KEO, KEO, KEO, H_DIM,
        0, 0, 0, 1.0f, 0, 0);

    // k-th smallest: x (fp32 exact 2-pass) -> slot 0
    hipMemsetAsync(histH, 0, 16384 * 4, stream);
    hist_x_hi<<<192, 256, 0, stream>>>(x, (long)SH / 4, histH);
    scan1<<<1, 256, 0, stream>>>(histH, 16384, sel, nullptr, (long)SH / 2, 0);
    hipMemsetAsync(histL, 0, 65536 * 4, stream);
    hist_x_lo<<<192, 256, 0, stream>>>(x, (long)SH / 4, sel, histL);
    scan1<<<1, 256, 0, stream>>>(histL, 65536, sel, out_kth + 0, 0, 1);
    // q,k,v,o (bf16 exact 1-pass) -> slots 1,2,3,5
    hipMemsetAsync(hist4, 0, 4 * 16384 * 4, stream);
    hist4_bf16<<<dim3(128, 4), 256, 0, stream>>>(qkvb, ob_ext, (long)SH / 8, hist4);
    scan4<<<4, 256, 0, stream>>>(hist4, out_kth, (long)SH / 2);
    // P -> slot 4
    hipMemsetAsync(histP, 0, 16384 * 4, stream);
    hist_bf16_p<<<1024, 256, 0, stream>>>((const unsigned short*)scores,
                                          (long)NHEAD * S_LEN * S_LEN / 8, histP);
    scan_bf16<<<1, 256, 0, stream>>>(histP, out_kth + 4,
                                     (long)NHEAD * S_LEN * S_LEN / 2);
}

// Round 7
// 805.078 us; speedup vs baseline: 1.7060x; 1.1935x over previous
//
#include <hip/hip_runtime.h>

#define S_LEN  1024
#define H_DIM  4096
#define NHEAD  32
#define HEAD_D 128
#define RANK   16
#define KE3    4160   // QKV extended K: 4096 + 3*16 + 16 pad (130 * 32)
#define KEO    4128   // O-proj extended K: 4096 + 16 + 16 pad (129 * 32)
#define TOTP   ((long)NHEAD * S_LEN * S_LEN)

typedef __bf16 bf16x8 __attribute__((ext_vector_type(8)));
typedef float  f32x4  __attribute__((ext_vector_type(4)));
typedef unsigned short ushort8v __attribute__((ext_vector_type(8)));

#define GLOAD_LDS16(g, l) __builtin_amdgcn_global_load_lds( \
    (const __attribute__((address_space(1))) unsigned int*)(g), \
    (__attribute__((address_space(3))) unsigned int*)(l), 16, 0, 0)

__device__ const float NF4_TAB[16] = {
    -1.0f, -0.6961928009986877f, -0.5250730514526367f, -0.39491748809814453f,
    -0.28444138169288635f, -0.18477343022823334f, -0.09105003625154495f, 0.0f,
    0.07958029955625534f, 0.16093020141124725f, 0.24611230194568634f,
    0.33791524171829224f, 0.4407098591327667f, 0.5626170039176941f,
    0.7229568362236023f, 1.0f};

__device__ __forceinline__ unsigned short f2bf(float f) {
    unsigned int u = __builtin_bit_cast(unsigned int, f);
    u = (u + 0x7FFFu + ((u >> 16) & 1u)) >> 16;   // RNE
    return (unsigned short)u;
}

__device__ __forceinline__ float bf2f(unsigned short s) {
    return __builtin_bit_cast(float, (unsigned int)s << 16);
}

// ---------------- plain dequant NF4 -> bf16, strided output row ----------------
__device__ __forceinline__ void dequant_body(
    const int* __restrict__ codes, const float* __restrict__ absmax,
    unsigned short* __restrict__ out, long i, int ostride) {
    int4 c0 = *(const int4*)(codes + i);
    int4 c1 = *(const int4*)(codes + i + 4);
    float am = absmax[i >> 6];
    long orow = i >> 12;                 // H_DIM = 4096
    int  col  = (int)(i & 4095);
    ushort8v r;
    r[0] = f2bf(NF4_TAB[c0.x] * am);
    r[1] = f2bf(NF4_TAB[c0.y] * am);
    r[2] = f2bf(NF4_TAB[c0.z] * am);
    r[3] = f2bf(NF4_TAB[c0.w] * am);
    r[4] = f2bf(NF4_TAB[c1.x] * am);
    r[5] = f2bf(NF4_TAB[c1.y] * am);
    r[6] = f2bf(NF4_TAB[c1.z] * am);
    r[7] = f2bf(NF4_TAB[c1.w] * am);
    *(ushort8v*)(out + orow * ostride + col) = r;
}

// ---------------- mega weight-prep: 4 dequants + lbT pads + bias gather --------
// grid dim3(9216, 4). bx<8192: dequant main region. bx>=8192: pad cols / bias.
__global__ __launch_bounds__(256) void prep_weights(
    const int* __restrict__ c0, const int* __restrict__ c1,
    const int* __restrict__ c2, const int* __restrict__ c3,
    const float* __restrict__ a0, const float* __restrict__ a1,
    const float* __restrict__ a2, const float* __restrict__ a3,
    const float* __restrict__ lb0, const float* __restrict__ lb1,
    const float* __restrict__ lb2, const float* __restrict__ lb3,
    const float* __restrict__ b0, const float* __restrict__ b1,
    const float* __restrict__ b2,
    unsigned short* __restrict__ wqkv, unsigned short* __restrict__ wo,
    float* __restrict__ bias3, long n) {
    int p = blockIdx.y;
    long bx = blockIdx.x;
    if (bx < 8192) {
        const int* codes = (p == 0) ? c0 : (p == 1) ? c1 : (p == 2) ? c2 : c3;
        const float* am  = (p == 0) ? a0 : (p == 1) ? a1 : (p == 2) ? a2 : a3;
        long i = (bx * 256 + threadIdx.x) * 8;
        if (i >= n) return;
        if (p < 3) dequant_body(codes, am, wqkv + (size_t)p * H_DIM * KE3, i, KE3);
        else       dequant_body(codes, am, wo, i, KEO);
    } else {
        long g = (bx - 8192) * 256 + threadIdx.x;
        if (p < 3) {
            // pad: 4096 rows x 64 cols; lbT_p at col offset 16p
            int row = (int)(g >> 6), c = (int)(g & 63);
            const float* lb = (p == 0) ? lb0 : (p == 1) ? lb1 : lb2;
            unsigned int r = (unsigned int)(c - 16 * p);
            float v = (r < 16u) ? lb[r * H_DIM + row] : 0.f;
            wqkv[(size_t)p * H_DIM * KE3 + (long)row * KE3 + 4096 + c] = f2bf(v);
            if (g < H_DIM) {
                const float* bp = (p == 0) ? b0 : (p == 1) ? b1 : b2;
                bias3[(size_t)p * H_DIM + g] = bp[g];
            }
        } else {
            if (g >= (long)H_DIM * 32) return;
            int row = (int)(g >> 5), c = (int)(g & 31);
            float v = (c < 16) ? lb3[c * H_DIM + row] : 0.f;
            wo[(long)row * KEO + 4096 + c] = f2bf(v);
        }
    }
}

// ---------------- fused x cast (fp32->bf16, stride KE3) + 3x lora_a ------------
// one block per row m; LDS stash of the x row; waves 0-2 compute xa_p (16 dots).
__global__ __launch_bounds__(256) void cast_lora(
    const float* __restrict__ x, const float* __restrict__ la0,
    const float* __restrict__ la1, const float* __restrict__ la2,
    unsigned short* __restrict__ xb_ext) {
    __shared__ float xs[4096];
    int m = blockIdx.x, tid = threadIdx.x;
    const float* xr = x + (long)m * H_DIM;
    int c = tid * 16;
    float4 f0 = *(const float4*)(xr + c);
    float4 f1 = *(const float4*)(xr + c + 4);
    float4 f2 = *(const float4*)(xr + c + 8);
    float4 f3 = *(const float4*)(xr + c + 12);
    *(float4*)(xs + c)      = f0;
    *(float4*)(xs + c + 4)  = f1;
    *(float4*)(xs + c + 8)  = f2;
    *(float4*)(xs + c + 12) = f3;
    ushort8v r0, r1;
    r0[0] = f2bf(f0.x); r0[1] = f2bf(f0.y); r0[2] = f2bf(f0.z); r0[3] = f2bf(f0.w);
    r0[4] = f2bf(f1.x); r0[5] = f2bf(f1.y); r0[6] = f2bf(f1.z); r0[7] = f2bf(f1.w);
    r1[0] = f2bf(f2.x); r1[1] = f2bf(f2.y); r1[2] = f2bf(f2.z); r1[3] = f2bf(f2.w);
    r1[4] = f2bf(f3.x); r1[5] = f2bf(f3.y); r1[6] = f2bf(f3.z); r1[7] = f2bf(f3.w);
    unsigned short* orow = xb_ext + (long)m * KE3 + c;
    *(ushort8v*)orow = r0;
    *(ushort8v*)(orow + 8) = r1;
    __syncthreads();
    int w = tid >> 6, lane = tid & 63;
    if (w < 3) {
        const float* la = (w == 0) ? la0 : (w == 1) ? la1 : la2;
        float s[16];
#pragma unroll
        for (int r = 0; r < 16; ++r) s[r] = 0.f;
        for (int k = lane; k < H_DIM; k += 64) {
            float xv = xs[k];
            const float4* lr = (const float4*)(la + (long)k * RANK);
            float4 q0 = lr[0], q1 = lr[1], q2 = lr[2], q3 = lr[3];
            s[0] += xv * q0.x;  s[1] += xv * q0.y;  s[2] += xv * q0.z;  s[3] += xv * q0.w;
            s[4] += xv * q1.x;  s[5] += xv * q1.y;  s[6] += xv * q1.z;  s[7] += xv * q1.w;
            s[8] += xv * q2.x;  s[9] += xv * q2.y;  s[10] += xv * q2.z; s[11] += xv * q2.w;
            s[12] += xv * q3.x; s[13] += xv * q3.y; s[14] += xv * q3.z; s[15] += xv * q3.w;
        }
        for (int off = 32; off; off >>= 1)
#pragma unroll
            for (int r = 0; r < 16; ++r) s[r] += __shfl_xor(s[r], off);
        if (lane == 0)
#pragma unroll
            for (int r = 0; r < 16; ++r)
                xb_ext[(long)m * KE3 + 4096 + 16 * w + r] = f2bf(s[r]);
    }
}

// ---------------- transpose v (bf16 [S][H]) -> vT (bf16 [H][S]) ----------------
__global__ void transpose_bf16_kernel(const unsigned short* __restrict__ v,
                                      unsigned short* __restrict__ vt) {
    __shared__ unsigned short tile[32][33];
    int c0 = blockIdx.x * 32, s0 = blockIdx.y * 32;
    int tx = threadIdx.x, ty = threadIdx.y;
    tile[ty][tx] = v[(long)(s0 + ty) * H_DIM + c0 + tx];
    __syncthreads();
    vt[(long)(c0 + ty) * S_LEN + s0 + tx] = tile[tx][ty];
}

// xa_o = ob @ la_o (bf16 in) -> bf16 cols of ob_ext
__global__ __launch_bounds__(256) void lora_ao_kernel(
    unsigned short* __restrict__ ob_ext, const float* __restrict__ la) {
    int m = blockIdx.x;
    const unsigned short* xr = ob_ext + (long)m * KEO;
    int tid = threadIdx.x, lane = tid & 63, wid = tid >> 6;
    float s[4] = {0.f, 0.f, 0.f, 0.f};
    for (int k = lane; k < H_DIM; k += 64) {
        float xv = bf2f(xr[k]);
        const float* lr = la + (long)k * RANK + wid * 4;
        s[0] += xv * lr[0]; s[1] += xv * lr[1];
        s[2] += xv * lr[2]; s[3] += xv * lr[3];
    }
    for (int off = 32; off; off >>= 1)
        for (int r = 0; r < 4; ++r) s[r] += __shfl_down(s[r], off);
    if (lane == 0)
        for (int r = 0; r < 4; ++r)
            ob_ext[(long)m * KEO + 4096 + wid * 4 + r] = f2bf(s[r]);
}

// ---------------- bf16 NT GEMM: C[m][n] = alpha*sum_k A[m][k]*B[n][k] (+bias[n]) ------
// mode 0: plain batched (z). mode 1: causal triangular grid (x=tri idx, z=head).
// mode 2: batched + K limited to bm+128 (causal PV). mode 3: split-K2 (z half -> Cv/Cv2).
__global__ __launch_bounds__(256) void gemm_nt(
    const unsigned short* __restrict__ A, const unsigned short* __restrict__ B,
    void* __restrict__ Cv, void* __restrict__ Cv2, const float* __restrict__ bias,
    int K, int lda, int ldb, int ldc,
    long strideA, long strideB, long strideC, float alpha, int mode, int obf) {
    int bm, bn;
    int k0s = 0, k0e = K;
    if (mode == 1) {
        int i = blockIdx.x;
        int tm = (int)((sqrtf(8.f * i + 1.f) - 1.f) * 0.5f);
        if ((tm + 1) * (tm + 2) / 2 <= i) tm++;
        if (tm * (tm + 1) / 2 > i) tm--;
        int tn = i - tm * (tm + 1) / 2;
        bm = tm * 128; bn = tn * 128;
    } else {
        bm = blockIdx.y * 128; bn = blockIdx.x * 128;
        if (mode == 2) { int kl = bm + 128; if (kl < k0e) k0e = kl; }
    }
    const unsigned short* Ab = A;
    const unsigned short* Bb = B;
    long coff = 0;
    void* Cuse = Cv;
    if (mode == 3) {
        int Kh = (K / 2) & ~31;
        k0s = blockIdx.z ? Kh : 0;
        k0e = blockIdx.z ? K : Kh;
        Cuse = blockIdx.z ? Cv2 : Cv;
    } else {
        Ab += (long)blockIdx.z * strideA;
        Bb += (long)blockIdx.z * strideB;
        coff = (long)blockIdx.z * strideC;
    }
    __shared__ unsigned short As[128][32];   // UNPADDED: global_load_lds lane-order
    __shared__ unsigned short Bs[128][32];
    const int tid = threadIdx.x;
    const int lane = tid & 63, wid = tid >> 6;
    const int wm = (wid >> 1) * 64, wn = (wid & 1) * 64;
    const int sr = wid * 16 + (lane >> 2);
    const int sc = (lane & 3) * 8;
    const unsigned short* gA0 = Ab + (long)(bm + sr) * lda + sc;
    const unsigned short* gA1 = gA0 + (long)64 * lda;
    const unsigned short* gB0 = Bb + (long)(bn + sr) * ldb + sc;
    const unsigned short* gB1 = gB0 + (long)64 * ldb;
    unsigned short* lA0 = &As[wid * 16][0];
    unsigned short* lA1 = &As[64 + wid * 16][0];
    unsigned short* lB0 = &Bs[wid * 16][0];
    unsigned short* lB1 = &Bs[64 + wid * 16][0];
    f32x4 acc[4][4] = {};
    const int kq = (lane >> 4) * 8;
    const int rr = lane & 15;
    for (int k0 = k0s; k0 < k0e; k0 += 32) {
        GLOAD_LDS16(gA0 + k0, lA0);
        GLOAD_LDS16(gA1 + k0, lA1);
        GLOAD_LDS16(gB0 + k0, lB0);
        GLOAD_LDS16(gB1 + k0, lB1);
        __syncthreads();
        bf16x8 af[4], bfr[4];
        for (int i = 0; i < 4; ++i) {
            uint4 ta = *(const uint4*)&As[wm + i * 16 + rr][kq];
            uint4 tb = *(const uint4*)&Bs[wn + i * 16 + rr][kq];
            af[i]  = __builtin_bit_cast(bf16x8, ta);
            bfr[i] = __builtin_bit_cast(bf16x8, tb);
        }
        for (int i = 0; i < 4; ++i)
            for (int j = 0; j < 4; ++j)
                acc[i][j] = __builtin_amdgcn_mfma_f32_16x16x32_bf16(
                    af[i], bfr[j], acc[i][j], 0, 0, 0);
        __syncthreads();
    }
    const int cr = (lane >> 4) * 4;
    const int cc = lane & 15;
    float bv[4];
#pragma unroll
    for (int j = 0; j < 4; ++j)
        bv[j] = bias ? bias[(long)blockIdx.z * H_DIM + bn + wn + j * 16 + cc] : 0.f;
    if (obf) {
        unsigned short* Cb = (unsigned short*)Cuse + coff;
        for (int i = 0; i < 4; ++i)
            for (int j = 0; j < 4; ++j) {
                unsigned short* cp = Cb + (long)(bm + wm + i * 16 + cr) * ldc
                                        + (bn + wn + j * 16 + cc);
                for (int r = 0; r < 4; ++r)
                    cp[(long)r * ldc] = f2bf(acc[i][j][r] * alpha + bv[j]);
            }
    } else {
        float* Cb = (float*)Cuse + coff;
        for (int i = 0; i < 4; ++i)
            for (int j = 0; j < 4; ++j) {
                float* cp = Cb + (long)(bm + wm + i * 16 + cr) * ldc
                               + (bn + wn + j * 16 + cc);
                for (int r = 0; r < 4; ++r)
                    cp[(long)r * ldc] = acc[i][j][r] * alpha + bv[j];
            }
    }
}

// ---------------- combine split-K partials + bias ----------------
__global__ __launch_bounds__(256) void combine_kernel(
    float* __restrict__ out, const float* __restrict__ part,
    const float* __restrict__ bias) {
    long idx = ((long)blockIdx.x * 256 + threadIdx.x) * 4;
    int n = (int)(idx & 4095);
    float4 o = *(float4*)(out + idx);
    float4 p = *(const float4*)(part + idx);
    float4 b = *(const float4*)(bias + n);
    o.x += p.x + b.x; o.y += p.y + b.y; o.z += p.z + b.z; o.w += p.w + b.w;
    *(float4*)(out + idx) = o;
}

// ---------------- causal softmax row, writes bf16 P in-place ----------------
__global__ __launch_bounds__(256) void softmax_causal(float* __restrict__ scores) {
    long rowbase = (long)blockIdx.x * S_LEN;
    int i = blockIdx.x & (S_LEN - 1);
    int tid = threadIdx.x, lane = tid & 63, wid = tid >> 6;
    float* row = scores + rowbase;
    int L = i + 1;
    float v[4];
    float mx = -1e30f;
    for (int t = 0; t < 4; ++t) {
        int j = tid + (t << 8);
        v[t] = (j < L) ? row[j] : -1e30f;
        mx = fmaxf(mx, v[t]);
    }
    for (int off = 32; off; off >>= 1) mx = fmaxf(mx, __shfl_xor(mx, off));
    __shared__ float red[4], red2[4];
    if (lane == 0) red[wid] = mx;
    __syncthreads();
    mx = fmaxf(fmaxf(red[0], red[1]), fmaxf(red[2], red[3]));
    float e[4], sum = 0.f;
    for (int t = 0; t < 4; ++t) {
        int j = tid + (t << 8);
        e[t] = (j < L) ? __expf(v[t] - mx) : 0.f;
        sum += e[t];
    }
    for (int off = 32; off; off >>= 1) sum += __shfl_xor(sum, off);
    if (lane == 0) red2[wid] = sum;
    __syncthreads();
    sum = red2[0] + red2[1] + red2[2] + red2[3];
    float inv = 1.f / sum;
    unsigned short* prow = (unsigned short*)scores + rowbase * 2;
    for (int t = 0; t < 4; ++t) {
        int j = tid + (t << 8);
        prow[j] = f2bf(e[t] * inv);
    }
}

// ---------------- mega histogram: 6 tensors in one dispatch ----------------
// y=0: x (fp32, abs hi-bits). y=1..3: q/k/v (bf16 contiguous). y=4: o (bf16,
// stride-KEO rows). y=5: P (bf16, stride-2048 rows incl. upper-tri zeros).
__global__ __launch_bounds__(256, 2) void hist6(
    const float* __restrict__ x, const unsigned short* __restrict__ qkv,
    const unsigned short* __restrict__ ob, const unsigned short* __restrict__ P,
    unsigned int* __restrict__ hist) {
    __shared__ unsigned int lh[16384];
    const long SH = (long)S_LEN * H_DIM;
    int t = threadIdx.x, ten = blockIdx.y;
    unsigned int* gh = hist + (long)ten * 16384;
    for (int b = t; b < 16384; b += 256) lh[b] = 0u;
    __syncthreads();
    long i = (long)blockIdx.x * 256 + t;
    long stride = (long)gridDim.x * 256;
    if (ten == 0) {
        for (; i < SH / 4; i += stride) {
            float4 v = *(const float4*)(x + i * 4);
            unsigned int u0 = (__builtin_bit_cast(unsigned int, v.x) & 0x7FFFFFFFu) >> 16;
            unsigned int u1 = (__builtin_bit_cast(unsigned int, v.y) & 0x7FFFFFFFu) >> 16;
            unsigned int u2 = (__builtin_bit_cast(unsigned int, v.z) & 0x7FFFFFFFu) >> 16;
            unsigned int u3 = (__builtin_bit_cast(unsigned int, v.w) & 0x7FFFFFFFu) >> 16;
            atomicAdd(&lh[u0 < 16384u ? u0 : 16383u], 1u);
            atomicAdd(&lh[u1 < 16384u ? u1 : 16383u], 1u);
            atomicAdd(&lh[u2 < 16384u ? u2 : 16383u], 1u);
            atomicAdd(&lh[u3 < 16384u ? u3 : 16383u], 1u);
        }
    } else if (ten <= 3) {
        const unsigned short* src = qkv + (size_t)(ten - 1) * SH;
        for (; i < SH / 8; i += stride) {
            ushort8v v = ((const ushort8v*)src)[i];
#pragma unroll
            for (int j = 0; j < 8; ++j) {
                unsigned int u = v[j] & 0x7FFFu;
                atomicAdd(&lh[u < 16384u ? u : 16383u], 1u);
            }
        }
    } else if (ten == 4) {
        for (; i < SH / 8; i += stride) {
            long off = (i >> 9) * KEO + ((i & 511) << 3);
            ushort8v v = *(const ushort8v*)(ob + off);
#pragma unroll
            for (int j = 0; j < 8; ++j) {
                unsigned int u = v[j] & 0x7FFFu;
                atomicAdd(&lh[u < 16384u ? u : 16383u], 1u);
            }
        }
    } else {
        unsigned int zc = 0;
        for (; i < TOTP / 8; i += stride) {
            long r = i >> 7;
            int c = (int)(i & 127) * 8;
            ushort8v v = *(const ushort8v*)(P + (r << 11) + c);
#pragma unroll
            for (int j = 0; j < 8; ++j) {
                unsigned int b = v[j];
                if (b == 0) zc++;
                else atomicAdd(&lh[b < 16384u ? b : 16383u], 1u);
            }
        }
        if (zc) atomicAdd(&lh[0], zc);
    }
    __syncthreads();
    for (int b = t; b < 16384; b += 256) {
        unsigned int c = lh[b];
        if (c) atomicAdd(&gh[b], c);
    }
}

// one block per tensor; k-th value = bin lower edge (exact for bf16 tensors)
__global__ __launch_bounds__(256) void scan6(
    const unsigned int* __restrict__ hist, float* __restrict__ out_kth) {
    int ten = blockIdx.x;
    const unsigned int* h = hist + (long)ten * 16384;
    __shared__ unsigned int part[256];
    int t = threadIdx.x;
    unsigned int s = 0;
    for (int b = 0; b < 64; ++b) s += h[t * 64 + b];
    part[t] = s;
    __syncthreads();
    if (t == 0) {
        long k = (ten == 5) ? TOTP / 2 : (long)S_LEN * H_DIM / 2;
        long c = 0;
        int ch = 0;
        for (; ch < 256; ++ch) {
            if (c + (long)part[ch] >= k) break;
            c += part[ch];
        }
        int bin = ch * 64;
        for (;; ++bin) {
            unsigned int hv = h[bin];
            if (c + (long)hv >= k) break;
            c += hv;
        }
        int slot = (ten == 4) ? 5 : (ten == 5) ? 4 : ten;
        out_kth[slot] = __builtin_bit_cast(float, (unsigned int)bin << 16);
    }
}

// ==================================================================
extern "C" void kernel_launch(void* const* d_in, const int* in_sizes, int n_in,
                              void* d_out, int out_size, void* d_ws, size_t ws_size,
                              hipStream_t stream) {
    (void)in_sizes; (void)n_in; (void)out_size; (void)ws_size;
    const float* x = (const float*)d_in[0];
    const int*   wcodes[4] = {(const int*)d_in[1], (const int*)d_in[6],
                              (const int*)d_in[11], (const int*)d_in[16]};
    const float* wabs[4]   = {(const float*)d_in[2], (const float*)d_in[7],
                              (const float*)d_in[12], (const float*)d_in[17]};
    const float* bias[4]   = {(const float*)d_in[3], (const float*)d_in[8],
                              (const float*)d_in[13], (const float*)d_in[18]};
    const float* lA[4]     = {(const float*)d_in[4], (const float*)d_in[9],
                              (const float*)d_in[14], (const float*)d_in[19]};
    const float* lB[4]     = {(const float*)d_in[5], (const float*)d_in[10],
                              (const float*)d_in[15], (const float*)d_in[20]};

    char* wp = (char*)d_ws;
    auto alloc = [&](size_t bytes) {
        char* p = wp; wp += (bytes + 255) & ~(size_t)255; return p;
    };
    const size_t SH  = (size_t)S_LEN * H_DIM;       // 4,194,304
    const long   nW  = (long)H_DIM * H_DIM;
    unsigned short* xb_ext = (unsigned short*)alloc((size_t)S_LEN * KE3 * 2);
    unsigned short* qkvb   = (unsigned short*)alloc(3 * SH * 2);  // q,k,v bf16
    unsigned short* vT     = (unsigned short*)alloc(SH * 2);
    unsigned short* ob_ext = (unsigned short*)alloc((size_t)S_LEN * KEO * 2);
    unsigned short* Wd_ext = (unsigned short*)alloc((size_t)H_DIM * KEO * 2);
    float*        opart  = (float*)alloc(SH * 4);
    float*        bias3  = (float*)alloc(3 * H_DIM * 4);
    unsigned int* hist   = (unsigned int*)alloc(6 * 16384 * 4);
    // scores (128 MB) doubles as Wqkv_ext buffer (102 MB) before attention
    float* scores = (float*)alloc((size_t)NHEAD * S_LEN * S_LEN * 4);
    unsigned short* Wqkv_ext = (unsigned short*)scores;

    float* out_final = (float*)d_out;
    float* out_kth   = out_final + SH;

    unsigned short* qb = qkvb;
    unsigned short* kb = qkvb + SH;
    unsigned short* vb = qkvb + 2 * SH;

    // 1) all weight prep in one dispatch (4 dequants + lbT pads + bias gather)
    prep_weights<<<dim3(9216, 4), 256, 0, stream>>>(
        wcodes[0], wcodes[1], wcodes[2], wcodes[3],
        wabs[0], wabs[1], wabs[2], wabs[3],
        lB[0], lB[1], lB[2], lB[3],
        bias[0], bias[1], bias[2],
        Wqkv_ext, Wd_ext, bias3, nW);

    // 2) x cast + xa columns (reads x once)
    cast_lora<<<S_LEN, 256, 0, stream>>>(x, lA[0], lA[1], lA[2], xb_ext);

    // 3) QKV: ONE z=3 batched GEMM over K=4160 (main + LoRA fused) -> bf16 + bias
    gemm_nt<<<dim3(32, 8, 3), 256, 0, stream>>>(
        xb_ext, Wqkv_ext, qkvb, nullptr, bias3, KE3, KE3, KE3, H_DIM,
        0, (long)H_DIM * KE3, (long)SH, 1.0f, 0, 1);

    // 4) v -> vT
    transpose_bf16_kernel<<<dim3(H_DIM / 32, S_LEN / 32), dim3(32, 32), 0, stream>>>(vb, vT);

    // 5) scores = q.kT / sqrt(128): 36 lower-triangular tiles per head
    gemm_nt<<<dim3(36, 1, NHEAD), 256, 0, stream>>>(
        qb, kb, scores, nullptr, nullptr, HEAD_D, H_DIM, H_DIM, S_LEN,
        128, 128, (long)S_LEN * S_LEN, 0.08838834764831845f, 1, 0);

    // 6) softmax -> bf16 P in-place
    softmax_causal<<<NHEAD * S_LEN, 256, 0, stream>>>(scores);

    // 7) o = P.v -> ob_ext (bf16, row stride KEO); mode 2 limits K to bm+128
    gemm_nt<<<dim3(1, 8, NHEAD), 256, 0, stream>>>(
        (const unsigned short*)scores, vT, ob_ext, nullptr, nullptr, S_LEN,
        2 * S_LEN, S_LEN, KEO,
        (long)S_LEN * 2 * S_LEN, (long)HEAD_D * S_LEN, 128, 1.0f, 2, 1);

    // 8) xa_o columns
    lora_ao_kernel<<<S_LEN, 256, 0, stream>>>(ob_ext, lA[3]);

    // 9) O projection: split-K2 (z=2, 512 blocks) -> out_final + opart
    gemm_nt<<<dim3(32, 8, 2), 256, 0, stream>>>(
        ob_ext, Wd_ext, out_final, opart, nullptr, KEO, KEO, KEO, H_DIM,
        0, 0, 0, 1.0f, 3, 0);

    // 10) combine partials + bias
    combine_kernel<<<4096, 256, 0, stream>>>(out_final, opart, bias[3]);

    // 11-13) k-th selects: one memset + one 6-tensor histogram + one scan
    hipMemsetAsync(hist, 0, 6 * 16384 * 4, stream);
    hist6<<<dim3(256, 6), 256, 0, stream>>>(
        x, qkvb, ob_ext, (const unsigned short*)scores, hist);
    scan6<<<6, 256, 0, stream>>>(hist, out_kth);
}